// Round 7
// baseline (565.468 us; speedup 1.0000x reference)
//
#include <hip/hip_runtime.h>

// GlobalFusion R11: k_merge1 adds T14 double-buffered register prefetch
// (viable now: acc[4][2]+ra0/ra1 ~ 84 VGPR vs R5's 96+spill). Next k-step's
// 16 strided loads fly across MFMA+fres+barrier. All else = R10 (565us).

#define DEV static __device__ __forceinline__

typedef __attribute__((ext_vector_type(8))) short short8x;
typedef __attribute__((ext_vector_type(4))) float f32x4;

constexpr int Bc = 2, Vc = 6, Cc = 128, Hc = 128, Wc = 128;
constexpr int Nc = Bc * Vc;      // 12
constexpr int Pc = Hc * Wc;      // 16384
constexpr int NPX = Nc * Pc;     // 196608

DEV float us2f(unsigned short u) {
  return __builtin_bit_cast(float, (unsigned int)u << 16);
}
DEV unsigned short f2us(float f) {
  unsigned int i = __builtin_bit_cast(unsigned int, f);
  unsigned int r = i + 0x7FFFu + ((i >> 16) & 1u);   // RNE
  return (unsigned short)(r >> 16);
}
DEV float geluf(float x) { return x * 0.5f * (1.f + erff(x * 0.70710678118654752f)); }
DEV float sigm(float x) { return 1.f / (1.f + __expf(-x)); }

// ---------------- weight prep: fp32 -> bf16 (+ GRU row interleave) ----------------
__global__ __launch_bounds__(256) void k_prepw(
    const float* __restrict__ w1, const float* __restrict__ w2,
    const float* __restrict__ wu, const float* __restrict__ gw,
    const float* __restrict__ gbw, unsigned short* __restrict__ wbf) {
  int idx = blockIdx.x * 256 + threadIdx.x;
  float v;
  if (idx < 32768) {
    v = w1[idx];
  } else if (idx < 49152) {
    v = w2[idx - 32768];
  } else if (idx < 65536) {
    v = wu[idx - 49152];
  } else {
    int i = (idx < 98304) ? (idx - 65536) : (idx - 98304);
    int np = i >> 7, k = i & 127;
    int j = np >> 5, s = np & 31;
    int src = (s < 16) ? (16 * j + s) : (128 + 16 * j + (s - 16));
    const float* w = (idx < 98304) ? gw : gbw;
    v = w[src * 128 + k];
  }
  wbf[idx] = f2us(v);
}

// ---------------- K1: merge 1x1 conv 256->128 + GELU (MFMA) ----------------
// R11: T14 pipeline. pack(cur) -> issue(next) -> barrier -> MFMA+fres.
__global__ __launch_bounds__(256) void k_merge1(
    const float* __restrict__ feats, const float* __restrict__ prj,
    const unsigned short* __restrict__ w1b, const float* __restrict__ b1,
    unsigned short* __restrict__ m1, unsigned short* __restrict__ fres) {
  __shared__ unsigned short sA[64][72];
  const int t = threadIdx.x;
  const int wave = t >> 6, lane = t & 63, quad = lane >> 4, lr = lane & 15;
  const int mb = blockIdx.x;
  const int n = mb >> 8;               // 256 blocks per n
  const int p0 = (mb & 255) << 6;      // 64-px group
  const size_t m0 = (size_t)n * Pc + p0;
  const int px = t & 63;               // this thread's A-row
  const int ho = t >> 6;               // 0..3: 16-channel quarter
  const int wn2 = wave * 32;           // wave's 32 output cols

  f32x4 acc[4][2];
#pragma unroll
  for (int i = 0; i < 4; i++)
#pragma unroll
    for (int j = 0; j < 2; j++) acc[i][j] = (f32x4){0.f, 0.f, 0.f, 0.f};

  float ra0[2][8], ra1[2][8];

  auto issueA = [&](int k0, float (&ra)[2][8]) {
#pragma unroll
    for (int g = 0; g < 2; ++g) {
      const int ch = k0 + ho * 16 + g * 8;
      const float* src = (ch < 128)
          ? (feats + (size_t)(n * 128 + ch) * Pc)
          : (prj + (size_t)(n * 128 + (ch - 128)) * Pc);
      src += p0 + px;
#pragma unroll
      for (int j = 0; j < 8; ++j) ra[g][j] = src[(size_t)j * Pc];
    }
  };
  auto packA = [&](float (&ra)[2][8]) {
#pragma unroll
    for (int g = 0; g < 2; ++g) {
      unsigned int pk[4];
#pragma unroll
      for (int q2 = 0; q2 < 4; ++q2)
        pk[q2] = (unsigned int)f2us(ra[g][2 * q2]) |
                 ((unsigned int)f2us(ra[g][2 * q2 + 1]) << 16);
      uint4 w4;
      w4.x = pk[0]; w4.y = pk[1]; w4.z = pk[2]; w4.w = pk[3];
      *(uint4*)&sA[px][ho * 16 + g * 8] = w4;
    }
  };
  auto gemmStep = [&](int k0) {
    short8x bf2[2][2];
#pragma unroll
    for (int ks = 0; ks < 2; ++ks)
#pragma unroll
      for (int j = 0; j < 2; j++)
        bf2[ks][j] = *reinterpret_cast<const short8x*>(
            w1b + (size_t)(wn2 + j * 16 + lr) * 256 + k0 + ks * 32 + quad * 8);
#pragma unroll
    for (int ks = 0; ks < 2; ++ks) {
      const int kk = ks * 32 + quad * 8;
      short8x a[4];
#pragma unroll
      for (int i = 0; i < 4; i++)
        a[i] = *reinterpret_cast<const short8x*>(&sA[i * 16 + lr][kk]);
#pragma unroll
      for (int i = 0; i < 4; i++)
#pragma unroll
        for (int j = 0; j < 2; j++)
          acc[i][j] = __builtin_amdgcn_mfma_f32_16x16x32_bf16(a[i], bf2[ks][j], acc[i][j], 0, 0, 0);
    }
  };
  auto fresStep = [&](int k0) {
    if (k0 < 128) {
      for (int u = t; u < 512; u += 256) {
        int row = u >> 3, seg = u & 7;
        *(uint4*)(fres + (m0 + row) * 128 + k0 + seg * 8) =
            *(const uint4*)&sA[row][seg * 8];
      }
    }
  };

  issueA(0, ra0);
  // step 0
  packA(ra0);
  issueA(64, ra1);
  __syncthreads();
  gemmStep(0); fresStep(0);
  // step 1
  __syncthreads();
  packA(ra1);
  issueA(128, ra0);
  __syncthreads();
  gemmStep(64); fresStep(64);
  // step 2
  __syncthreads();
  packA(ra0);
  issueA(192, ra1);
  __syncthreads();
  gemmStep(128); fresStep(128);
  // step 3
  __syncthreads();
  packA(ra1);
  __syncthreads();
  gemmStep(192); fresStep(192);

#pragma unroll
  for (int i = 0; i < 4; i++)
#pragma unroll
    for (int r = 0; r < 4; r++) {
      size_t row = m0 + i * 16 + quad * 4 + r;
#pragma unroll
      for (int j = 0; j < 2; j++) {
        int c = wn2 + j * 16 + lr;
        m1[row * 128 + c] = f2us(geluf(acc[i][j][r] + b1[c]));
      }
    }
}

// ---------------- K2: depthwise 3x3 + GELU ([px][c] layout) ----------------
__global__ __launch_bounds__(256) void k_dw(
    const unsigned short* __restrict__ in, const float* __restrict__ wd,
    const float* __restrict__ bd, unsigned short* __restrict__ out) {
  __shared__ float w[Cc * 9];
  for (int i = threadIdx.x; i < Cc * 9; i += 256) w[i] = wd[i];
  __syncthreads();
  const int wave = threadIdx.x >> 6, lane = threadIdx.x & 63;
  const int gid = blockIdx.x * 4 + wave;       // 4-px group id over NPX/4
  const int n = gid >> 12, p4 = (gid & 4095) << 2;
  const int y = p4 >> 7, x0 = p4 & 127;        // x0 in {0,4,...,124}
  const int c0 = 2 * lane;
  const float* w0 = w + c0 * 9;
  const float* w1 = w + (c0 + 1) * 9;
  float a0[4], a1[4];
#pragma unroll
  for (int k = 0; k < 4; ++k) { a0[k] = bd[c0]; a1[k] = bd[c0 + 1]; }
#pragma unroll
  for (int dy = 0; dy < 3; ++dy) {
    int yy = y + dy - 1;
    if (yy < 0 || yy >= Hc) continue;
    const unsigned short* rowp = in + ((size_t)(n * Pc + yy * Wc)) * 128 + c0;
    float tx[6], ty[6];
#pragma unroll
    for (int j = 0; j < 6; ++j) {
      int xx = x0 + j - 1;
      if (xx >= 0 && xx < Wc) {
        ushort2 v = *(const ushort2*)(rowp + (size_t)xx * 128);
        tx[j] = us2f(v.x); ty[j] = us2f(v.y);
      } else { tx[j] = 0.f; ty[j] = 0.f; }
    }
#pragma unroll
    for (int k = 0; k < 4; ++k)
#pragma unroll
      for (int dx = 0; dx < 3; ++dx) {
        a0[k] += w0[dy * 3 + dx] * tx[k + dx];
        a1[k] += w1[dy * 3 + dx] * ty[k + dx];
      }
  }
#pragma unroll
  for (int k = 0; k < 4; ++k) {
    ushort2 pk;
    pk.x = f2us(geluf(a0[k]));
    pk.y = f2us(geluf(a1[k]));
    *(ushort2*)(out + ((size_t)(n * Pc) + p4 + k) * 128 + c0) = pk;
  }
}

// ---------------- K3: merge 1x1 conv 128->128 + bias + residual (MFMA) ----------------
__global__ __launch_bounds__(256) void k_merge2(
    const unsigned short* __restrict__ A, const unsigned short* __restrict__ w2b,
    const float* __restrict__ b2, const unsigned short* __restrict__ fres,
    unsigned short* __restrict__ X1) {
  __shared__ unsigned short sA[128][72];
  __shared__ unsigned short sB[128][72];
  const int t = threadIdx.x;
  const int wave = t >> 6, lane = t & 63, quad = lane >> 4, lr = lane & 15;
  const int wm = (wave >> 1) * 64, wn = (wave & 1) * 64;
  const size_t m0 = (size_t)blockIdx.x * 128;
  f32x4 acc[4][4];
#pragma unroll
  for (int i = 0; i < 4; i++)
#pragma unroll
    for (int j = 0; j < 4; j++) acc[i][j] = (f32x4){0.f, 0.f, 0.f, 0.f};

  for (int k0 = 0; k0 < 128; k0 += 64) {
    for (int u = t; u < 1024; u += 256) {
      int row = u >> 3, seg = u & 7;
      *(uint4*)&sA[row][seg * 8] =
          *(const uint4*)(A + (m0 + row) * 128 + k0 + seg * 8);
    }
    for (int u = t; u < 1024; u += 256) {
      int row = u >> 3, seg = u & 7;
      *(uint4*)&sB[row][seg * 8] =
          *(const uint4*)(w2b + (size_t)row * 128 + k0 + seg * 8);
    }
    __syncthreads();
#pragma unroll
    for (int ks = 0; ks < 2; ++ks) {
      const int kk = ks * 32 + quad * 8;
      short8x a[4], bf[4];
#pragma unroll
      for (int i = 0; i < 4; i++)
        a[i] = *reinterpret_cast<const short8x*>(&sA[wm + i * 16 + lr][kk]);
#pragma unroll
      for (int j = 0; j < 4; j++)
        bf[j] = *reinterpret_cast<const short8x*>(&sB[wn + j * 16 + lr][kk]);
#pragma unroll
      for (int i = 0; i < 4; i++)
#pragma unroll
        for (int j = 0; j < 4; j++)
          acc[i][j] = __builtin_amdgcn_mfma_f32_16x16x32_bf16(a[i], bf[j], acc[i][j], 0, 0, 0);
    }
    __syncthreads();
  }
#pragma unroll
  for (int i = 0; i < 4; i++)
#pragma unroll
    for (int r = 0; r < 4; r++) {
      size_t row = m0 + wm + i * 16 + quad * 4 + r;
#pragma unroll
      for (int j = 0; j < 4; j++) {
        int c = wn + j * 16 + lr;
        float v = acc[i][j][r] + b2[c] + us2f(fres[row * 128 + c]);
        X1[row * 128 + c] = f2us(v);
      }
    }
}

// ---------------- K4: fused bidirectional minGRU (MFMA + scans) ----------------
__global__ __launch_bounds__(512) void k_gru(
    const unsigned short* __restrict__ X1, const unsigned short* __restrict__ Wg,
    const unsigned short* __restrict__ Wb, unsigned short* __restrict__ F2) {
  __shared__ unsigned short sA[96][72];
  __shared__ unsigned short sH[96][136];
  const int t = threadIdx.x;
  const int wave = t >> 6, lane = t & 63, quad = lane >> 4, lr = lane & 15;
  const int blk = blockIdx.x;
  const int b = blk >> 10, p0 = (blk & 1023) << 4;
  f32x4 acc[6][2];
#pragma unroll
  for (int v = 0; v < 6; v++)
#pragma unroll
    for (int j = 0; j < 2; j++) acc[v][j] = (f32x4){0.f, 0.f, 0.f, 0.f};

  // ---- GEMM1: hg1 = X1 . Wg^T (Wg rows interleaved; B JIT from global) ----
#pragma unroll 1
  for (int k0 = 0; k0 < 128; k0 += 64) {
    __syncthreads();
    for (int u = t; u < 768; u += 512) {
      int r = u >> 3, seg = u & 7;
      int v = r >> 4, ps = r & 15;
      *(uint4*)&sA[r][seg * 8] =
          *(const uint4*)(X1 + ((size_t)((b * 6 + v) * Pc + p0 + ps)) * 128 + k0 + seg * 8);
    }
    __syncthreads();
#pragma unroll
    for (int ks = 0; ks < 2; ++ks) {
      const int kk = ks * 32 + quad * 8;
      short8x a[6], bf[2];
#pragma unroll
      for (int j = 0; j < 2; j++)
        bf[j] = *reinterpret_cast<const short8x*>(
            Wg + (size_t)(wave * 32 + j * 16 + lr) * 128 + k0 + kk);
#pragma unroll
      for (int v = 0; v < 6; v++)
        a[v] = *reinterpret_cast<const short8x*>(&sA[v * 16 + lr][kk]);
#pragma unroll
      for (int v = 0; v < 6; v++)
#pragma unroll
        for (int j = 0; j < 2; j++)
          acc[v][j] = __builtin_amdgcn_mfma_f32_16x16x32_bf16(a[v], bf[j], acc[v][j], 0, 0, 0);
    }
  }
  __syncthreads();
  // ---- scan1 -> sH [row][hdim] ----
#pragma unroll
  for (int r = 0; r < 4; r++) {
    float h = 0.f;
#pragma unroll
    for (int v = 0; v < 6; v++) {
      float hid = acc[v][0][r], gat = acc[v][1][r];
      float z = sigm(gat);
      float ht = (hid >= 0.f) ? (hid + 0.5f) : sigm(hid);
      h = (1.f - z) * h + z * ht;
      sH[v * 16 + quad * 4 + r][wave * 16 + lr] = f2us(h);
    }
  }
  __syncthreads();

  // ---- GEMM2: hg2 = h1 . Wb^T (B JIT from global) ----
#pragma unroll
  for (int v = 0; v < 6; v++)
#pragma unroll
    for (int j = 0; j < 2; j++) acc[v][j] = (f32x4){0.f, 0.f, 0.f, 0.f};
#pragma unroll 1
  for (int k0 = 0; k0 < 128; k0 += 64) {
#pragma unroll
    for (int ks = 0; ks < 2; ++ks) {
      const int kk = ks * 32 + quad * 8;
      short8x a[6], bf[2];
#pragma unroll
      for (int j = 0; j < 2; j++)
        bf[j] = *reinterpret_cast<const short8x*>(
            Wb + (size_t)(wave * 32 + j * 16 + lr) * 128 + k0 + kk);
#pragma unroll
      for (int v = 0; v < 6; v++)
        a[v] = *reinterpret_cast<const short8x*>(&sH[v * 16 + lr][k0 + kk]);
#pragma unroll
      for (int v = 0; v < 6; v++)
#pragma unroll
        for (int j = 0; j < 2; j++)
          acc[v][j] = __builtin_amdgcn_mfma_f32_16x16x32_bf16(a[v], bf[j], acc[v][j], 0, 0, 0);
    }
  }
  // ---- scan2 -> F2 global ----
#pragma unroll
  for (int r = 0; r < 4; r++) {
    float h = 0.f;
#pragma unroll
    for (int v = 0; v < 6; v++) {
      float hid = acc[v][0][r], gat = acc[v][1][r];
      float z = sigm(gat);
      float ht = (hid >= 0.f) ? (hid + 0.5f) : sigm(hid);
      h = (1.f - z) * h + z * ht;
      F2[((size_t)((b * 6 + v) * Pc + p0 + quad * 4 + r)) * 128 + wave * 16 + lr] =
          f2us(h);
    }
  }
}

// ---------------- K5+K6 fused: alpha 3x3 conv + softmax over V + pool ----------------
__global__ __launch_bounds__(256) void k_apool(
    const unsigned short* __restrict__ F, const float* __restrict__ wa,
    const float* __restrict__ ba, unsigned short* __restrict__ P2) {
  __shared__ float w[Cc * 9];
  for (int i = threadIdx.x; i < Cc * 9; i += 256) w[i] = wa[i];
  __syncthreads();
  const int wave = threadIdx.x >> 6, lane = threadIdx.x & 63;
  const int px = blockIdx.x * 4 + wave;   // over B*P
  const int b = px >> 14, p = px & (Pc - 1);
  const int y = p >> 7, x = p & 127;
  const int c0 = 2 * lane;
  const float* w0 = w + c0 * 9;
  const float* w1 = w + (c0 + 1) * 9;
  float av[Vc];
  ushort2 ctr[Vc];
#pragma unroll
  for (int v = 0; v < Vc; ++v) {
    const unsigned short* Fv = F + ((size_t)((b * Vc + v) * Pc)) * 128;
    float acc = 0.f;
#pragma unroll
    for (int dy = 0; dy < 3; ++dy) {
      int yy = y + dy - 1;
      if (yy < 0 || yy >= Hc) continue;
#pragma unroll
      for (int dx = 0; dx < 3; ++dx) {
        int xx = x + dx - 1;
        if (xx < 0 || xx >= Wc) continue;
        const unsigned short* row = Fv + ((size_t)(yy * Wc + xx)) * 128;
        ushort2 vv = *(const ushort2*)(row + c0);
        if (dy == 1 && dx == 1) ctr[v] = vv;   // center tap always in-bounds
        acc += w0[dy * 3 + dx] * us2f(vv.x) + w1[dy * 3 + dx] * us2f(vv.y);
      }
    }
#pragma unroll
    for (int off = 32; off >= 1; off >>= 1) acc += __shfl_xor(acc, off);
    av[v] = acc + ba[0];
  }
  float mx = -1e30f;
#pragma unroll
  for (int v = 0; v < Vc; ++v) mx = fmaxf(mx, av[v]);
  float s = 0.f;
#pragma unroll
  for (int v = 0; v < Vc; ++v) { av[v] = __expf(av[v] - mx); s += av[v]; }
  const float inv = 1.f / s;
  float a0 = 0.f, a1 = 0.f;
#pragma unroll
  for (int v = 0; v < Vc; ++v) {
    float sw = av[v] * inv;
    a0 += us2f(ctr[v].x) * sw;
    a1 += us2f(ctr[v].y) * sw;
  }
  ushort2 pk;
  pk.x = f2us(a0);
  pk.y = f2us(a1);
  *(ushort2*)(P2 + (size_t)px * 128 + c0) = pk;
}

// ---------------- K7: up 1x1 conv + pixel_shuffle(4) (MFMA) ----------------
__global__ __launch_bounds__(256) void k_up(
    const unsigned short* __restrict__ A, const unsigned short* __restrict__ wub,
    const float* __restrict__ bu, unsigned short* __restrict__ us_) {
  __shared__ unsigned short sA[128][72];
  __shared__ unsigned short sB[128][72];
  const int t = threadIdx.x;
  const int wave = t >> 6, lane = t & 63, quad = lane >> 4, lr = lane & 15;
  const int wm = (wave >> 1) * 64, wn = (wave & 1) * 64;
  const size_t m0 = (size_t)blockIdx.x * 128;
  f32x4 acc[4][4];
#pragma unroll
  for (int i = 0; i < 4; i++)
#pragma unroll
    for (int j = 0; j < 4; j++) acc[i][j] = (f32x4){0.f, 0.f, 0.f, 0.f};

  for (int k0 = 0; k0 < 128; k0 += 64) {
    for (int u = t; u < 1024; u += 256) {
      int row = u >> 3, seg = u & 7;
      *(uint4*)&sA[row][seg * 8] =
          *(const uint4*)(A + (m0 + row) * 128 + k0 + seg * 8);
    }
    for (int u = t; u < 1024; u += 256) {
      int row = u >> 3, seg = u & 7;
      *(uint4*)&sB[row][seg * 8] =
          *(const uint4*)(wub + (size_t)row * 128 + k0 + seg * 8);
    }
    __syncthreads();
#pragma unroll
    for (int ks = 0; ks < 2; ++ks) {
      const int kk = ks * 32 + quad * 8;
      short8x a[4], bf[4];
#pragma unroll
      for (int i = 0; i < 4; i++)
        a[i] = *reinterpret_cast<const short8x*>(&sA[wm + i * 16 + lr][kk]);
#pragma unroll
      for (int j = 0; j < 4; j++)
        bf[j] = *reinterpret_cast<const short8x*>(&sB[wn + j * 16 + lr][kk]);
#pragma unroll
      for (int i = 0; i < 4; i++)
#pragma unroll
        for (int j = 0; j < 4; j++)
          acc[i][j] = __builtin_amdgcn_mfma_f32_16x16x32_bf16(a[i], bf[j], acc[i][j], 0, 0, 0);
    }
    __syncthreads();
  }
#pragma unroll
  for (int i = 0; i < 4; i++)
#pragma unroll
    for (int r = 0; r < 4; r++) {
      size_t row = m0 + wm + i * 16 + quad * 4 + r;   // global pixel (b*P + p)
      int b = (int)(row >> 14), p = (int)(row & (Pc - 1));
      int y = p >> 7, x = p & 127;
#pragma unroll
      for (int j = 0; j < 4; j++) {
        int c = wn + j * 16 + lr;
        float v = acc[i][j][r] + bu[c];
        int co = c >> 4, r1 = (c >> 2) & 3, r2 = c & 3;
        us_[(((size_t)b * 8 + co) * 512 + (y * 4 + r1)) * 512 + (x * 4 + r2)] = f2us(v);
      }
    }
}

// ---------------- K8: 3x3 conv 8->3 on 512x512, fp32 output ----------------
__global__ __launch_bounds__(256) void k_outc(
    const unsigned short* __restrict__ us_, const float* __restrict__ wo,
    const float* __restrict__ bo, float* __restrict__ out) {
  __shared__ float w[3 * 8 * 9];
  for (int i = threadIdx.x; i < 216; i += 256) w[i] = wo[i];
  __syncthreads();
  int i = blockIdx.x;
  const int xh = i & 1; i >>= 1;
  const int Y = i & 511; i >>= 9;
  const int b = i;
  const int X = xh * 256 + threadIdx.x;
  float a0 = bo[0], a1 = bo[1], a2 = bo[2];
  for (int ci = 0; ci < 8; ++ci) {
    const unsigned short* pl = us_ + ((size_t)b * 8 + ci) * 512 * 512;
    const float* w0 = w + 0 * 72 + ci * 9;
    const float* w1 = w + 1 * 72 + ci * 9;
    const float* w2 = w + 2 * 72 + ci * 9;
#pragma unroll
    for (int dy = 0; dy < 3; ++dy) {
      int YY = Y + dy - 1;
      if (YY < 0 || YY >= 512) continue;
#pragma unroll
      for (int dx = 0; dx < 3; ++dx) {
        int XX = X + dx - 1;
        if (XX < 0 || XX >= 512) continue;
        float v = us2f(pl[(size_t)YY * 512 + XX]);
        a0 += w0[dy * 3 + dx] * v;
        a1 += w1[dy * 3 + dx] * v;
        a2 += w2[dy * 3 + dx] * v;
      }
    }
  }
  out[(((size_t)b * 3 + 0) * 512 + Y) * 512 + X] = a0;
  out[(((size_t)b * 3 + 1) * 512 + Y) * 512 + X] = a1;
  out[(((size_t)b * 3 + 2) * 512 + Y) * 512 + X] = a2;
}

// ---------------- launcher ----------------
extern "C" void kernel_launch(void* const* d_in, const int* in_sizes, int n_in,
                              void* d_out, int out_size, void* d_ws, size_t ws_size,
                              hipStream_t stream) {
  const float* feats = (const float*)d_in[0];
  const float* prj = (const float*)d_in[1];
  const float* w1 = (const float*)d_in[2];
  const float* b1 = (const float*)d_in[3];
  const float* wd = (const float*)d_in[4];
  const float* bd = (const float*)d_in[5];
  const float* w2 = (const float*)d_in[6];
  const float* b2 = (const float*)d_in[7];
  const float* gw = (const float*)d_in[8];
  const float* gbw = (const float*)d_in[9];
  const float* wa = (const float*)d_in[10];
  const float* ba = (const float*)d_in[11];
  const float* wu = (const float*)d_in[12];
  const float* bu = (const float*)d_in[13];
  const float* wo = (const float*)d_in[14];
  const float* bo = (const float*)d_in[15];
  float* out = (float*)d_out;

  char* ws = (char*)d_ws;
  // big buffers (bf16 [px][128], 50,331,648 B each):
  unsigned short* buf0 = (unsigned short*)(ws + 0);            // m1, then X1
  unsigned short* buf1 = (unsigned short*)(ws + 50331648);     // dwout, then F2
  unsigned short* fres = (unsigned short*)(ws + 100663296);    // bf16 feats
  unsigned short* P2 = (unsigned short*)(ws + 151781376);      // 8,388,608
  unsigned short* ushuf = (unsigned short*)(ws + 160169984);   // 8,388,608
  unsigned short* wbf = (unsigned short*)(ws + 168558592);     // 262,144

  const unsigned short* w1b = wbf;
  const unsigned short* w2b = wbf + 32768;
  const unsigned short* wub = wbf + 49152;
  const unsigned short* wgi = wbf + 65536;
  const unsigned short* wgbi = wbf + 98304;

  dim3 blk(256);
  k_prepw<<<dim3(512), blk, 0, stream>>>(w1, w2, wu, gw, gbw, wbf);
  k_merge1<<<dim3(NPX / 64), blk, 0, stream>>>(feats, prj, w1b, b1, buf0, fres);
  k_dw<<<dim3(NPX / 16), blk, 0, stream>>>(buf0, wd, bd, buf1);
  k_merge2<<<dim3(NPX / 128), blk, 0, stream>>>(buf1, w2b, b2, fres, buf0);
  k_gru<<<dim3(Bc * (Pc / 16)), dim3(512), 0, stream>>>(buf0, wgi, wgbi, buf1);
  k_apool<<<dim3(Bc * Pc / 4), blk, 0, stream>>>(buf1, wa, ba, P2);
  k_up<<<dim3(Bc * Pc / 128), blk, 0, stream>>>(P2, wub, bu, ushuf);
  k_outc<<<dim3(2 * 512 * 2), blk, 0, stream>>>(ushuf, wo, bo, out);

  (void)in_sizes; (void)n_in; (void)out_size; (void)ws_size;
}

// Round 8
// 538.982 us; speedup vs baseline: 1.0491x; 1.0491x over previous
//
#include <hip/hip_runtime.h>

// GlobalFusion R12: merge1 reverted to R10 (T14 regressed, R11 125us ->
// 101us). NEW: k_dw + k_merge2 fused into k_dwm2 (depthwise 3x3+GELU
// computed straight into the GEMM A-tile in LDS; saves 100MB dwout
// round-trip + one launch). Bit-identical math order throughout.

#define DEV static __device__ __forceinline__

typedef __attribute__((ext_vector_type(8))) short short8x;
typedef __attribute__((ext_vector_type(4))) float f32x4;

constexpr int Bc = 2, Vc = 6, Cc = 128, Hc = 128, Wc = 128;
constexpr int Nc = Bc * Vc;      // 12
constexpr int Pc = Hc * Wc;      // 16384
constexpr int NPX = Nc * Pc;     // 196608

DEV float us2f(unsigned short u) {
  return __builtin_bit_cast(float, (unsigned int)u << 16);
}
DEV unsigned short f2us(float f) {
  unsigned int i = __builtin_bit_cast(unsigned int, f);
  unsigned int r = i + 0x7FFFu + ((i >> 16) & 1u);   // RNE
  return (unsigned short)(r >> 16);
}
DEV float geluf(float x) { return x * 0.5f * (1.f + erff(x * 0.70710678118654752f)); }
DEV float sigm(float x) { return 1.f / (1.f + __expf(-x)); }

// ---------------- weight prep: fp32 -> bf16 (+ GRU row interleave) ----------------
__global__ __launch_bounds__(256) void k_prepw(
    const float* __restrict__ w1, const float* __restrict__ w2,
    const float* __restrict__ wu, const float* __restrict__ gw,
    const float* __restrict__ gbw, unsigned short* __restrict__ wbf) {
  int idx = blockIdx.x * 256 + threadIdx.x;
  float v;
  if (idx < 32768) {
    v = w1[idx];
  } else if (idx < 49152) {
    v = w2[idx - 32768];
  } else if (idx < 65536) {
    v = wu[idx - 49152];
  } else {
    int i = (idx < 98304) ? (idx - 65536) : (idx - 98304);
    int np = i >> 7, k = i & 127;
    int j = np >> 5, s = np & 31;
    int src = (s < 16) ? (16 * j + s) : (128 + 16 * j + (s - 16));
    const float* w = (idx < 98304) ? gw : gbw;
    v = w[src * 128 + k];
  }
  wbf[idx] = f2us(v);
}

// ---------------- K1: merge 1x1 conv 256->128 + GELU (MFMA) — R10 version ----------------
__global__ __launch_bounds__(256) void k_merge1(
    const float* __restrict__ feats, const float* __restrict__ prj,
    const unsigned short* __restrict__ w1b, const float* __restrict__ b1,
    unsigned short* __restrict__ m1, unsigned short* __restrict__ fres) {
  __shared__ unsigned short sA[64][72];
  const int t = threadIdx.x;
  const int wave = t >> 6, lane = t & 63, quad = lane >> 4, lr = lane & 15;
  const int mb = blockIdx.x;
  const int n = mb >> 8;               // 256 blocks per n
  const int p0 = (mb & 255) << 6;      // 64-px group
  const size_t m0 = (size_t)n * Pc + p0;
  const int px = t & 63;               // this thread's A-row
  const int ho = t >> 6;               // 0..3: 16-channel quarter
  const int wn2 = wave * 32;           // wave's 32 output cols

  f32x4 acc[4][2];
#pragma unroll
  for (int i = 0; i < 4; i++)
#pragma unroll
    for (int j = 0; j < 2; j++) acc[i][j] = (f32x4){0.f, 0.f, 0.f, 0.f};

#pragma unroll 1
  for (int s = 0; s < 4; ++s) {
    const int k0 = s * 64;
    float ra[2][8];
#pragma unroll
    for (int g = 0; g < 2; ++g) {
      const int ch = k0 + ho * 16 + g * 8;
      const float* src = (ch < 128)
          ? (feats + (size_t)(n * 128 + ch) * Pc)
          : (prj + (size_t)(n * 128 + (ch - 128)) * Pc);
      src += p0 + px;
#pragma unroll
      for (int j = 0; j < 8; ++j) ra[g][j] = src[(size_t)j * Pc];
    }
    __syncthreads();          // prev MFMA + fres reads of sA done
#pragma unroll
    for (int g = 0; g < 2; ++g) {
      unsigned int pk[4];
#pragma unroll
      for (int q2 = 0; q2 < 4; ++q2)
        pk[q2] = (unsigned int)f2us(ra[g][2 * q2]) |
                 ((unsigned int)f2us(ra[g][2 * q2 + 1]) << 16);
      uint4 w4;
      w4.x = pk[0]; w4.y = pk[1]; w4.z = pk[2]; w4.w = pk[3];
      *(uint4*)&sA[px][ho * 16 + g * 8] = w4;
    }
    __syncthreads();
    // JIT B fragments (L2-hit) + MFMA
    short8x bf2[2][2];
#pragma unroll
    for (int ks = 0; ks < 2; ++ks)
#pragma unroll
      for (int j = 0; j < 2; j++)
        bf2[ks][j] = *reinterpret_cast<const short8x*>(
            w1b + (size_t)(wn2 + j * 16 + lr) * 256 + k0 + ks * 32 + quad * 8);
#pragma unroll
    for (int ks = 0; ks < 2; ++ks) {
      const int kk = ks * 32 + quad * 8;
      short8x a[4];
#pragma unroll
      for (int i = 0; i < 4; i++)
        a[i] = *reinterpret_cast<const short8x*>(&sA[i * 16 + lr][kk]);
#pragma unroll
      for (int i = 0; i < 4; i++)
#pragma unroll
        for (int j = 0; j < 2; j++)
          acc[i][j] = __builtin_amdgcn_mfma_f32_16x16x32_bf16(a[i], bf2[ks][j], acc[i][j], 0, 0, 0);
    }
    if (k0 < 128) {   // feats slice passthrough -> fres (reads sA)
      for (int u = t; u < 512; u += 256) {
        int row = u >> 3, seg = u & 7;
        *(uint4*)(fres + (m0 + row) * 128 + k0 + seg * 8) =
            *(const uint4*)&sA[row][seg * 8];
      }
    }
  }
#pragma unroll
  for (int i = 0; i < 4; i++)
#pragma unroll
    for (int r = 0; r < 4; r++) {
      size_t row = m0 + i * 16 + quad * 4 + r;
#pragma unroll
      for (int j = 0; j < 2; j++) {
        int c = wn2 + j * 16 + lr;
        m1[row * 128 + c] = f2us(geluf(acc[i][j][r] + b1[c]));
      }
    }
}

// ---------------- K2+K3 fused: depthwise 3x3 + GELU -> 1x1 conv + residual ----------------
// Block = 64 px. Phase 1: thread (oct=t&15, pxq=t>>4) computes dw+GELU for
// 4 px x 8 ch straight into sA (b128 writes, ~2-way conflicts). m1 taps read
// from global (L2/L3-resident). Phase 2: merge2 GEMM (B JIT from w2b) +
// bias + residual -> X1. Tap order & k-order identical to split kernels.
__global__ __launch_bounds__(256) void k_dwm2(
    const unsigned short* __restrict__ m1, const float* __restrict__ wd,
    const float* __restrict__ bd, const unsigned short* __restrict__ w2b,
    const float* __restrict__ b2, const unsigned short* __restrict__ fres,
    unsigned short* __restrict__ X1) {
  __shared__ unsigned short sA[64][72];
  __shared__ float wdt[9 * 128];    // transposed [tap][ch]
  __shared__ float bds[128];
  const int t = threadIdx.x;
  const int wave = t >> 6, lane = t & 63, quad = lane >> 4, lr = lane & 15;
  const int mb = blockIdx.x;
  const int n = mb >> 8;
  const int p0 = (mb & 255) << 6;
  const size_t m0 = (size_t)n * Pc + p0;
  const int y = p0 >> 7, xbase = p0 & 127;
  const int wn2 = wave * 32;

  for (int i = t; i < 1152; i += 256) {
    int ch = i / 9, tap = i - ch * 9;
    wdt[tap * 128 + ch] = wd[i];
  }
  for (int i = t; i < 128; i += 256) bds[i] = bd[i];
  __syncthreads();

  // ---- phase 1: depthwise 3x3 + GELU ----
  {
    const int oct = t & 15, pxq = t >> 4;
    const int ch0 = oct * 8;
    float acc8[4][8];
#pragma unroll
    for (int p = 0; p < 4; ++p)
#pragma unroll
      for (int e = 0; e < 8; ++e) acc8[p][e] = bds[ch0 + e];
#pragma unroll
    for (int dy = 0; dy < 3; ++dy) {
      int yy = y + dy - 1;
      if (yy < 0 || yy >= Hc) continue;
      const unsigned short* rowp = m1 + ((size_t)(n * Pc + yy * Wc)) * 128 + ch0;
#pragma unroll
      for (int dx = 0; dx < 3; ++dx) {
        float wreg[8];
        *(float4*)&wreg[0] = *(const float4*)&wdt[(dy * 3 + dx) * 128 + ch0];
        *(float4*)&wreg[4] = *(const float4*)&wdt[(dy * 3 + dx) * 128 + ch0 + 4];
#pragma unroll
        for (int p = 0; p < 4; ++p) {
          int xx = xbase + pxq * 4 + p + dx - 1;
          if (xx < 0 || xx >= Wc) continue;
          short8x v = *reinterpret_cast<const short8x*>(rowp + (size_t)xx * 128);
#pragma unroll
          for (int e = 0; e < 8; ++e)
            acc8[p][e] += wreg[e] * us2f((unsigned short)v[e]);
        }
      }
    }
#pragma unroll
    for (int p = 0; p < 4; ++p) {
      unsigned int pk[4];
#pragma unroll
      for (int q2 = 0; q2 < 4; ++q2)
        pk[q2] = (unsigned int)f2us(geluf(acc8[p][2 * q2])) |
                 ((unsigned int)f2us(geluf(acc8[p][2 * q2 + 1])) << 16);
      uint4 w4;
      w4.x = pk[0]; w4.y = pk[1]; w4.z = pk[2]; w4.w = pk[3];
      *(uint4*)&sA[pxq * 4 + p][ch0] = w4;
    }
  }
  __syncthreads();

  // ---- phase 2: merge2 GEMM (K=128), bias + residual ----
  f32x4 acc[4][2];
#pragma unroll
  for (int i = 0; i < 4; i++)
#pragma unroll
    for (int j = 0; j < 2; j++) acc[i][j] = (f32x4){0.f, 0.f, 0.f, 0.f};
#pragma unroll
  for (int k0 = 0; k0 < 128; k0 += 64) {
    short8x bf2[2][2];
#pragma unroll
    for (int ks = 0; ks < 2; ++ks)
#pragma unroll
      for (int j = 0; j < 2; j++)
        bf2[ks][j] = *reinterpret_cast<const short8x*>(
            w2b + (size_t)(wn2 + j * 16 + lr) * 128 + k0 + ks * 32 + quad * 8);
#pragma unroll
    for (int ks = 0; ks < 2; ++ks) {
      const int kk = k0 + ks * 32 + quad * 8;
      short8x a[4];
#pragma unroll
      for (int i = 0; i < 4; i++)
        a[i] = *reinterpret_cast<const short8x*>(&sA[i * 16 + lr][kk]);
#pragma unroll
      for (int i = 0; i < 4; i++)
#pragma unroll
        for (int j = 0; j < 2; j++)
          acc[i][j] = __builtin_amdgcn_mfma_f32_16x16x32_bf16(a[i], bf2[ks][j], acc[i][j], 0, 0, 0);
    }
  }
#pragma unroll
  for (int i = 0; i < 4; i++)
#pragma unroll
    for (int r = 0; r < 4; r++) {
      size_t row = m0 + i * 16 + quad * 4 + r;
#pragma unroll
      for (int j = 0; j < 2; j++) {
        int c = wn2 + j * 16 + lr;
        float v = acc[i][j][r] + b2[c] + us2f(fres[row * 128 + c]);
        X1[row * 128 + c] = f2us(v);
      }
    }
}

// ---------------- K4: fused bidirectional minGRU (MFMA + scans) ----------------
__global__ __launch_bounds__(512) void k_gru(
    const unsigned short* __restrict__ X1, const unsigned short* __restrict__ Wg,
    const unsigned short* __restrict__ Wb, unsigned short* __restrict__ F2) {
  __shared__ unsigned short sA[96][72];
  __shared__ unsigned short sH[96][136];
  const int t = threadIdx.x;
  const int wave = t >> 6, lane = t & 63, quad = lane >> 4, lr = lane & 15;
  const int blk = blockIdx.x;
  const int b = blk >> 10, p0 = (blk & 1023) << 4;
  f32x4 acc[6][2];
#pragma unroll
  for (int v = 0; v < 6; v++)
#pragma unroll
    for (int j = 0; j < 2; j++) acc[v][j] = (f32x4){0.f, 0.f, 0.f, 0.f};

  // ---- GEMM1: hg1 = X1 . Wg^T (Wg rows interleaved; B JIT from global) ----
#pragma unroll 1
  for (int k0 = 0; k0 < 128; k0 += 64) {
    __syncthreads();
    for (int u = t; u < 768; u += 512) {
      int r = u >> 3, seg = u & 7;
      int v = r >> 4, ps = r & 15;
      *(uint4*)&sA[r][seg * 8] =
          *(const uint4*)(X1 + ((size_t)((b * 6 + v) * Pc + p0 + ps)) * 128 + k0 + seg * 8);
    }
    __syncthreads();
#pragma unroll
    for (int ks = 0; ks < 2; ++ks) {
      const int kk = ks * 32 + quad * 8;
      short8x a[6], bf[2];
#pragma unroll
      for (int j = 0; j < 2; j++)
        bf[j] = *reinterpret_cast<const short8x*>(
            Wg + (size_t)(wave * 32 + j * 16 + lr) * 128 + k0 + kk);
#pragma unroll
      for (int v = 0; v < 6; v++)
        a[v] = *reinterpret_cast<const short8x*>(&sA[v * 16 + lr][kk]);
#pragma unroll
      for (int v = 0; v < 6; v++)
#pragma unroll
        for (int j = 0; j < 2; j++)
          acc[v][j] = __builtin_amdgcn_mfma_f32_16x16x32_bf16(a[v], bf[j], acc[v][j], 0, 0, 0);
    }
  }
  __syncthreads();
  // ---- scan1 -> sH [row][hdim] ----
#pragma unroll
  for (int r = 0; r < 4; r++) {
    float h = 0.f;
#pragma unroll
    for (int v = 0; v < 6; v++) {
      float hid = acc[v][0][r], gat = acc[v][1][r];
      float z = sigm(gat);
      float ht = (hid >= 0.f) ? (hid + 0.5f) : sigm(hid);
      h = (1.f - z) * h + z * ht;
      sH[v * 16 + quad * 4 + r][wave * 16 + lr] = f2us(h);
    }
  }
  __syncthreads();

  // ---- GEMM2: hg2 = h1 . Wb^T (B JIT from global) ----
#pragma unroll
  for (int v = 0; v < 6; v++)
#pragma unroll
    for (int j = 0; j < 2; j++) acc[v][j] = (f32x4){0.f, 0.f, 0.f, 0.f};
#pragma unroll 1
  for (int k0 = 0; k0 < 128; k0 += 64) {
#pragma unroll
    for (int ks = 0; ks < 2; ++ks) {
      const int kk = ks * 32 + quad * 8;
      short8x a[6], bf[2];
#pragma unroll
      for (int j = 0; j < 2; j++)
        bf[j] = *reinterpret_cast<const short8x*>(
            Wb + (size_t)(wave * 32 + j * 16 + lr) * 128 + k0 + kk);
#pragma unroll
      for (int v = 0; v < 6; v++)
        a[v] = *reinterpret_cast<const short8x*>(&sH[v * 16 + lr][k0 + kk]);
#pragma unroll
      for (int v = 0; v < 6; v++)
#pragma unroll
        for (int j = 0; j < 2; j++)
          acc[v][j] = __builtin_amdgcn_mfma_f32_16x16x32_bf16(a[v], bf[j], acc[v][j], 0, 0, 0);
    }
  }
  // ---- scan2 -> F2 global ----
#pragma unroll
  for (int r = 0; r < 4; r++) {
    float h = 0.f;
#pragma unroll
    for (int v = 0; v < 6; v++) {
      float hid = acc[v][0][r], gat = acc[v][1][r];
      float z = sigm(gat);
      float ht = (hid >= 0.f) ? (hid + 0.5f) : sigm(hid);
      h = (1.f - z) * h + z * ht;
      F2[((size_t)((b * 6 + v) * Pc + p0 + quad * 4 + r)) * 128 + wave * 16 + lr] =
          f2us(h);
    }
  }
}

// ---------------- K5+K6 fused: alpha 3x3 conv + softmax over V + pool ----------------
__global__ __launch_bounds__(256) void k_apool(
    const unsigned short* __restrict__ F, const float* __restrict__ wa,
    const float* __restrict__ ba, unsigned short* __restrict__ P2) {
  __shared__ float w[Cc * 9];
  for (int i = threadIdx.x; i < Cc * 9; i += 256) w[i] = wa[i];
  __syncthreads();
  const int wave = threadIdx.x >> 6, lane = threadIdx.x & 63;
  const int px = blockIdx.x * 4 + wave;   // over B*P
  const int b = px >> 14, p = px & (Pc - 1);
  const int y = p >> 7, x = p & 127;
  const int c0 = 2 * lane;
  const float* w0 = w + c0 * 9;
  const float* w1 = w + (c0 + 1) * 9;
  float av[Vc];
  ushort2 ctr[Vc];
#pragma unroll
  for (int v = 0; v < Vc; ++v) {
    const unsigned short* Fv = F + ((size_t)((b * Vc + v) * Pc)) * 128;
    float acc = 0.f;
#pragma unroll
    for (int dy = 0; dy < 3; ++dy) {
      int yy = y + dy - 1;
      if (yy < 0 || yy >= Hc) continue;
#pragma unroll
      for (int dx = 0; dx < 3; ++dx) {
        int xx = x + dx - 1;
        if (xx < 0 || xx >= Wc) continue;
        const unsigned short* row = Fv + ((size_t)(yy * Wc + xx)) * 128;
        ushort2 vv = *(const ushort2*)(row + c0);
        if (dy == 1 && dx == 1) ctr[v] = vv;   // center tap always in-bounds
        acc += w0[dy * 3 + dx] * us2f(vv.x) + w1[dy * 3 + dx] * us2f(vv.y);
      }
    }
#pragma unroll
    for (int off = 32; off >= 1; off >>= 1) acc += __shfl_xor(acc, off);
    av[v] = acc + ba[0];
  }
  float mx = -1e30f;
#pragma unroll
  for (int v = 0; v < Vc; ++v) mx = fmaxf(mx, av[v]);
  float s = 0.f;
#pragma unroll
  for (int v = 0; v < Vc; ++v) { av[v] = __expf(av[v] - mx); s += av[v]; }
  const float inv = 1.f / s;
  float a0 = 0.f, a1 = 0.f;
#pragma unroll
  for (int v = 0; v < Vc; ++v) {
    float sw = av[v] * inv;
    a0 += us2f(ctr[v].x) * sw;
    a1 += us2f(ctr[v].y) * sw;
  }
  ushort2 pk;
  pk.x = f2us(a0);
  pk.y = f2us(a1);
  *(ushort2*)(P2 + (size_t)px * 128 + c0) = pk;
}

// ---------------- K7: up 1x1 conv + pixel_shuffle(4) (MFMA) ----------------
__global__ __launch_bounds__(256) void k_up(
    const unsigned short* __restrict__ A, const unsigned short* __restrict__ wub,
    const float* __restrict__ bu, unsigned short* __restrict__ us_) {
  __shared__ unsigned short sA[128][72];
  __shared__ unsigned short sB[128][72];
  const int t = threadIdx.x;
  const int wave = t >> 6, lane = t & 63, quad = lane >> 4, lr = lane & 15;
  const int wm = (wave >> 1) * 64, wn = (wave & 1) * 64;
  const size_t m0 = (size_t)blockIdx.x * 128;
  f32x4 acc[4][4];
#pragma unroll
  for (int i = 0; i < 4; i++)
#pragma unroll
    for (int j = 0; j < 4; j++) acc[i][j] = (f32x4){0.f, 0.f, 0.f, 0.f};

  for (int k0 = 0; k0 < 128; k0 += 64) {
    for (int u = t; u < 1024; u += 256) {
      int row = u >> 3, seg = u & 7;
      *(uint4*)&sA[row][seg * 8] =
          *(const uint4*)(A + (m0 + row) * 128 + k0 + seg * 8);
    }
    for (int u = t; u < 1024; u += 256) {
      int row = u >> 3, seg = u & 7;
      *(uint4*)&sB[row][seg * 8] =
          *(const uint4*)(wub + (size_t)row * 128 + k0 + seg * 8);
    }
    __syncthreads();
#pragma unroll
    for (int ks = 0; ks < 2; ++ks) {
      const int kk = ks * 32 + quad * 8;
      short8x a[4], bf[4];
#pragma unroll
      for (int i = 0; i < 4; i++)
        a[i] = *reinterpret_cast<const short8x*>(&sA[wm + i * 16 + lr][kk]);
#pragma unroll
      for (int j = 0; j < 4; j++)
        bf[j] = *reinterpret_cast<const short8x*>(&sB[wn + j * 16 + lr][kk]);
#pragma unroll
      for (int i = 0; i < 4; i++)
#pragma unroll
        for (int j = 0; j < 4; j++)
          acc[i][j] = __builtin_amdgcn_mfma_f32_16x16x32_bf16(a[i], bf[j], acc[i][j], 0, 0, 0);
    }
    __syncthreads();
  }
#pragma unroll
  for (int i = 0; i < 4; i++)
#pragma unroll
    for (int r = 0; r < 4; r++) {
      size_t row = m0 + wm + i * 16 + quad * 4 + r;   // global pixel (b*P + p)
      int b = (int)(row >> 14), p = (int)(row & (Pc - 1));
      int y = p >> 7, x = p & 127;
#pragma unroll
      for (int j = 0; j < 4; j++) {
        int c = wn + j * 16 + lr;
        float v = acc[i][j][r] + bu[c];
        int co = c >> 4, r1 = (c >> 2) & 3, r2 = c & 3;
        us_[(((size_t)b * 8 + co) * 512 + (y * 4 + r1)) * 512 + (x * 4 + r2)] = f2us(v);
      }
    }
}

// ---------------- K8: 3x3 conv 8->3 on 512x512, fp32 output ----------------
__global__ __launch_bounds__(256) void k_outc(
    const unsigned short* __restrict__ us_, const float* __restrict__ wo,
    const float* __restrict__ bo, float* __restrict__ out) {
  __shared__ float w[3 * 8 * 9];
  for (int i = threadIdx.x; i < 216; i += 256) w[i] = wo[i];
  __syncthreads();
  int i = blockIdx.x;
  const int xh = i & 1; i >>= 1;
  const int Y = i & 511; i >>= 9;
  const int b = i;
  const int X = xh * 256 + threadIdx.x;
  float a0 = bo[0], a1 = bo[1], a2 = bo[2];
  for (int ci = 0; ci < 8; ++ci) {
    const unsigned short* pl = us_ + ((size_t)b * 8 + ci) * 512 * 512;
    const float* w0 = w + 0 * 72 + ci * 9;
    const float* w1 = w + 1 * 72 + ci * 9;
    const float* w2 = w + 2 * 72 + ci * 9;
#pragma unroll
    for (int dy = 0; dy < 3; ++dy) {
      int YY = Y + dy - 1;
      if (YY < 0 || YY >= 512) continue;
#pragma unroll
      for (int dx = 0; dx < 3; ++dx) {
        int XX = X + dx - 1;
        if (XX < 0 || XX >= 512) continue;
        float v = us2f(pl[(size_t)YY * 512 + XX]);
        a0 += w0[dy * 3 + dx] * v;
        a1 += w1[dy * 3 + dx] * v;
        a2 += w2[dy * 3 + dx] * v;
      }
    }
  }
  out[(((size_t)b * 3 + 0) * 512 + Y) * 512 + X] = a0;
  out[(((size_t)b * 3 + 1) * 512 + Y) * 512 + X] = a1;
  out[(((size_t)b * 3 + 2) * 512 + Y) * 512 + X] = a2;
}

// ---------------- launcher ----------------
extern "C" void kernel_launch(void* const* d_in, const int* in_sizes, int n_in,
                              void* d_out, int out_size, void* d_ws, size_t ws_size,
                              hipStream_t stream) {
  const float* feats = (const float*)d_in[0];
  const float* prj = (const float*)d_in[1];
  const float* w1 = (const float*)d_in[2];
  const float* b1 = (const float*)d_in[3];
  const float* wd = (const float*)d_in[4];
  const float* bd = (const float*)d_in[5];
  const float* w2 = (const float*)d_in[6];
  const float* b2 = (const float*)d_in[7];
  const float* gw = (const float*)d_in[8];
  const float* gbw = (const float*)d_in[9];
  const float* wa = (const float*)d_in[10];
  const float* ba = (const float*)d_in[11];
  const float* wu = (const float*)d_in[12];
  const float* bu = (const float*)d_in[13];
  const float* wo = (const float*)d_in[14];
  const float* bo = (const float*)d_in[15];
  float* out = (float*)d_out;

  char* ws = (char*)d_ws;
  // big buffers (bf16 [px][128], 50,331,648 B each):
  unsigned short* buf0 = (unsigned short*)(ws + 0);            // m1, then F2
  unsigned short* buf1 = (unsigned short*)(ws + 50331648);     // X1
  unsigned short* fres = (unsigned short*)(ws + 100663296);    // bf16 feats
  unsigned short* P2 = (unsigned short*)(ws + 151781376);      // 8,388,608
  unsigned short* ushuf = (unsigned short*)(ws + 160169984);   // 8,388,608
  unsigned short* wbf = (unsigned short*)(ws + 168558592);     // 262,144

  const unsigned short* w1b = wbf;
  const unsigned short* w2b = wbf + 32768;
  const unsigned short* wub = wbf + 49152;
  const unsigned short* wgi = wbf + 65536;
  const unsigned short* wgbi = wbf + 98304;

  dim3 blk(256);
  k_prepw<<<dim3(512), blk, 0, stream>>>(w1, w2, wu, gw, gbw, wbf);
  k_merge1<<<dim3(NPX / 64), blk, 0, stream>>>(feats, prj, w1b, b1, buf0, fres);
  k_dwm2<<<dim3(NPX / 64), blk, 0, stream>>>(buf0, wd, bd, w2b, b2, fres, buf1);
  k_gru<<<dim3(Bc * (Pc / 16)), dim3(512), 0, stream>>>(buf1, wgi, wgbi, buf0);
  k_apool<<<dim3(Bc * Pc / 4), blk, 0, stream>>>(buf0, wa, ba, P2);
  k_up<<<dim3(Bc * Pc / 128), blk, 0, stream>>>(P2, wub, bu, ushuf);
  k_outc<<<dim3(2 * 512 * 2), blk, 0, stream>>>(ushuf, wo, bo, out);

  (void)in_sizes; (void)n_in; (void)out_size; (void)ws_size;
}